// Round 1
// baseline (364.999 us; speedup 1.0000x reference)
//
#include <hip/hip_runtime.h>

// SHConv: out[b,o,n] = sum_i x[b,i,n] * W_{l(n)}[i,o],  l(n) = floor(sqrt(n))
// x: (32,64,6561) f32, weight: (64,64,17,1) f32, out: (32,64,6561) f32
// W_l is linear interpolation of 17 control points: 81 distinct 64x64 matrices.

#define NTOT 6561      // (L+1)^2
#define NL   81        // L+1 degrees
#define CH   64        // in_ch = out_ch = 64
#define BATCH 32
#define WTAB_ELEMS (NL * CH * CH)   // 331776 floats = 1.3 MB

// ---- Kernel A: build interpolated weight table, layout wt[l][o][i] ----
__global__ __launch_bounds__(256) void interp_kernel(const float* __restrict__ w,
                                                     float* __restrict__ wt) {
  int idx = blockIdx.x * 256 + threadIdx.x;      // exact: 1296*256 = 331776
  int l = idx >> 12;
  int o = (idx >> 6) & 63;
  int i = idx & 63;
  int cp; float f;
  if (l < 75) { cp = l / 5; f = (float)(l - cp * 5) * 0.2f; }   // 15 intervals of 5
  else        { cp = 15;    f = (float)(l - 75) * 0.2f; }        // tail interval2 = 5
  const float* wp = w + ((size_t)(i * 64 + o) * 17 + cp);        // weight[i][o][cp], cp stride 1
  wt[idx] = (1.0f - f) * wp[0] + f * wp[1];
}

// ---- shared inner loop: one wave, lane = out channel, wcf[64] in registers ----
__device__ __forceinline__ void compute_positions(const float* __restrict__ xb,
                                                  float* __restrict__ ob,
                                                  const float (&wcf)[64],
                                                  int p0, int p1) {
  int p = p0;
  for (; p + 4 <= p1; p += 4) {
    float a0 = 0.f, a1 = 0.f, a2 = 0.f, a3 = 0.f;
#pragma unroll
    for (int i = 0; i < 64; ++i) {
      float4 xv;                                          // N odd -> rows unaligned;
      __builtin_memcpy(&xv, xb + (size_t)i * NTOT + p, 16); // HW allows align-4 dwordx4
      a0 = fmaf(xv.x, wcf[i], a0);
      a1 = fmaf(xv.y, wcf[i], a1);
      a2 = fmaf(xv.z, wcf[i], a2);
      a3 = fmaf(xv.w, wcf[i], a3);
    }
    float4 acc = make_float4(a0, a1, a2, a3);
    __builtin_memcpy(ob + p, &acc, 16);
  }
  for (; p < p1; ++p) {
    float a = 0.f;
#pragma unroll
    for (int i = 0; i < 64; ++i)
      a = fmaf(xb[(size_t)i * NTOT + p], wcf[i], a);
    ob[p] = a;
  }
}

// ---- Kernel B (ws path): grid (81, 32); 4 waves split the 2l+1 positions ----
__global__ __launch_bounds__(256) void shconv_ws(const float* __restrict__ x,
                                                 const float* __restrict__ wt,
                                                 float* __restrict__ out) {
  int l = blockIdx.x;
  int b = blockIdx.y;
  int wv = threadIdx.x >> 6;
  int lane = threadIdx.x & 63;                  // lane = out channel

  float wcf[64];
  const float* wrow = wt + (size_t)(l * 64 + lane) * 64;   // wt[l][lane][i], 256B aligned
#pragma unroll
  for (int k = 0; k < 16; ++k) {
    float4 v = *(const float4*)(wrow + 4 * k);
    wcf[4 * k]     = v.x;
    wcf[4 * k + 1] = v.y;
    wcf[4 * k + 2] = v.z;
    wcf[4 * k + 3] = v.w;
  }

  int P = 2 * l + 1;
  int chunk = (P + 3) >> 2;
  int p0 = wv * chunk;
  if (p0 >= P) return;
  int p1 = min(P, p0 + chunk);

  size_t nbase = (size_t)l * l;
  const float* xb = x + (size_t)b * 64 * NTOT + nbase;
  float* ob = out + ((size_t)b * 64 + lane) * NTOT + nbase;
  compute_positions(xb, ob, wcf, p0, p1);
}

// ---- Kernel B (fallback, no ws): grid (81, 8); per-block LDS interpolation ----
__global__ __launch_bounds__(256) void shconv_lds(const float* __restrict__ x,
                                                  const float* __restrict__ w,
                                                  float* __restrict__ out) {
  __shared__ float wl[64][68];                  // pad 64->68 to break bank pattern
  int l = blockIdx.x;
  int cp; float f;
  if (l < 75) { cp = l / 5; f = (float)(l - cp * 5) * 0.2f; }
  else        { cp = 15;    f = (float)(l - 75) * 0.2f; }
  for (int e = threadIdx.x; e < 4096; e += 256) {
    int o = e >> 6, i = e & 63;
    const float* wp = w + ((size_t)(i * 64 + o) * 17 + cp);
    wl[o][i] = (1.0f - f) * wp[0] + f * wp[1];
  }
  __syncthreads();

  int wv = threadIdx.x >> 6;
  int lane = threadIdx.x & 63;
  float wcf[64];
#pragma unroll
  for (int k = 0; k < 16; ++k) {
    float4 v = *(const float4*)&wl[lane][4 * k];  // row base 272B: 16B-aligned
    wcf[4 * k]     = v.x;
    wcf[4 * k + 1] = v.y;
    wcf[4 * k + 2] = v.z;
    wcf[4 * k + 3] = v.w;
  }

  int b = blockIdx.y * 4 + wv;                   // one wave per batch, 4 batches/block
  int P = 2 * l + 1;
  size_t nbase = (size_t)l * l;
  const float* xb = x + (size_t)b * 64 * NTOT + nbase;
  float* ob = out + ((size_t)b * 64 + lane) * NTOT + nbase;
  compute_positions(xb, ob, wcf, 0, P);
}

extern "C" void kernel_launch(void* const* d_in, const int* in_sizes, int n_in,
                              void* d_out, int out_size, void* d_ws, size_t ws_size,
                              hipStream_t stream) {
  const float* x = (const float*)d_in[0];
  const float* w = (const float*)d_in[1];
  float* out = (float*)d_out;

  if (ws_size >= (size_t)WTAB_ELEMS * sizeof(float) && d_ws != nullptr) {
    float* wt = (float*)d_ws;
    hipLaunchKernelGGL(interp_kernel, dim3(WTAB_ELEMS / 256), dim3(256), 0, stream, w, wt);
    hipLaunchKernelGGL(shconv_ws, dim3(NL, BATCH), dim3(256), 0, stream, x, wt, out);
  } else {
    hipLaunchKernelGGL(shconv_lds, dim3(NL, 8), dim3(256), 0, stream, x, w, out);
  }
}

// Round 2
// 68.154 us; speedup vs baseline: 5.3555x; 5.3555x over previous
//
#include <hip/hip_runtime.h>

// SHConv: out[b,o,n] = sum_i x[b,i,n] * W_{l(n)}[i,o],  l(n) = floor(sqrt(n))
// x: (32,64,6561) f32, weight: (64,64,17,1) f32, out: (32,64,6561) f32
//
// Layout: lane = position n (coalesced loads AND stores), acc[o] in registers,
// weights broadcast from LDS. Degrees paired (l, 80-l) -> 162 positions/block
// (constant work). Each thread handles 2 batches to amortize LDS weight reads
// (8 FMA per ds_read_b128 -> FMA-bound, not LDS-bound).

#define NTOT 6561
#define CH   64

__global__ __launch_bounds__(192) void shconv_kernel(const float* __restrict__ x,
                                                     const float* __restrict__ w,
                                                     float* __restrict__ out) {
  __shared__ float wl[2][64][64];          // [sel][i][o], o contiguous
  const int l1 = blockIdx.x;               // 0..40
  const int l2 = 80 - l1;                  // 40..80
  const int P1 = 2 * l1 + 1;
  const int P2 = (l1 == 40) ? 0 : 2 * l2 + 1;   // avoid double-computing l=40

  // interpolation params (uniform per block): 15 intervals of 5, tail of 5
  int cp1, cp2; float f1, f2;
  if (l1 < 75) { cp1 = l1 / 5; f1 = (float)(l1 - cp1 * 5) * 0.2f; }
  else         { cp1 = 15;     f1 = (float)(l1 - 75) * 0.2f; }
  if (l2 < 75) { cp2 = l2 / 5; f2 = (float)(l2 - cp2 * 5) * 0.2f; }
  else         { cp2 = 15;     f2 = (float)(l2 - 75) * 0.2f; }

  const int tid = threadIdx.x;

  // interpolate both 64x64 weight tiles into LDS (weight is L2-resident)
  for (int e = tid; e < 8192; e += 192) {
    int sel = e >> 12;
    int r = e & 4095;
    int i = r >> 6, o = r & 63;
    int cp = sel ? cp2 : cp1;
    float f = sel ? f2 : f1;
    const float* wp = w + (size_t)(i * 64 + o) * 17 + cp;
    wl[sel][i][o] = (1.0f - f) * wp[0] + f * wp[1];
  }
  __syncthreads();

  const int Ptot = P1 + P2;                // 162 (81 for the l=40 block)
  if (tid >= Ptot) return;

  int sel, l, p;
  if (tid < P1) { sel = 0; l = l1; p = tid; }
  else          { sel = 1; l = l2; p = tid - P1; }
  const size_t nidx = (size_t)(l * l) + p; // position within the N axis

  const int b0 = blockIdx.y;               // 0..15
  const int b1 = b0 + 16;
  const float* x0 = x + (size_t)b0 * CH * NTOT + nidx;
  const float* x1 = x + (size_t)b1 * CH * NTOT + nidx;

  float acc0[64], acc1[64];
#pragma unroll
  for (int o = 0; o < 64; ++o) { acc0[o] = 0.f; acc1[o] = 0.f; }

  const float* wbase = &wl[sel][0][0];
#pragma unroll 4
  for (int i = 0; i < 64; ++i) {
    float xv0 = x0[(size_t)i * NTOT];      // coalesced across lanes
    float xv1 = x1[(size_t)i * NTOT];
    const float* wr = wbase + i * 64;
#pragma unroll
    for (int o = 0; o < 64; o += 4) {
      float4 wv = *(const float4*)(wr + o);   // uniform LDS broadcast (<=2-way)
      acc0[o]     = fmaf(xv0, wv.x, acc0[o]);
      acc0[o + 1] = fmaf(xv0, wv.y, acc0[o + 1]);
      acc0[o + 2] = fmaf(xv0, wv.z, acc0[o + 2]);
      acc0[o + 3] = fmaf(xv0, wv.w, acc0[o + 3]);
      acc1[o]     = fmaf(xv1, wv.x, acc1[o]);
      acc1[o + 1] = fmaf(xv1, wv.y, acc1[o + 1]);
      acc1[o + 2] = fmaf(xv1, wv.z, acc1[o + 2]);
      acc1[o + 3] = fmaf(xv1, wv.w, acc1[o + 3]);
    }
  }

  float* o0 = out + (size_t)b0 * CH * NTOT + nidx;
  float* o1 = out + (size_t)b1 * CH * NTOT + nidx;
#pragma unroll
  for (int o = 0; o < 64; ++o) {
    o0[(size_t)o * NTOT] = acc0[o];        // coalesced across lanes
    o1[(size_t)o * NTOT] = acc1[o];
  }
}

extern "C" void kernel_launch(void* const* d_in, const int* in_sizes, int n_in,
                              void* d_out, int out_size, void* d_ws, size_t ws_size,
                              hipStream_t stream) {
  const float* x = (const float*)d_in[0];
  const float* w = (const float*)d_in[1];
  float* out = (float*)d_out;
  hipLaunchKernelGGL(shconv_kernel, dim3(41, 16), dim3(192), 0, stream, x, w, out);
}

// Round 3
// 56.997 us; speedup vs baseline: 6.4038x; 1.1957x over previous
//
#include <hip/hip_runtime.h>

// SHConv: out[b,o,n] = sum_i x[b,i,n] * W_{l(n)}[i,o],  l(n) = floor(sqrt(n))
// x: (32,64,6561) f32, weight: (64,64,17,1) f32, out: (32,64,6561) f32
//
// R2 design: precompute wt[l][i][o] (81*64*64 f32, 1.3 MB) in d_ws.
// Main kernel: one 64-lane wave per (l, batch, 64-position chunk).
//   lane = position  -> coalesced x loads and out stores (R2's clean WRITE path)
//   acc[64 out-ch]   -> fits in VGPRs (no spill, unlike 128-acc version)
//   weights          -> block-uniform address -> scalar (SGPR) loads, no LDS at all.
// Grid = exact wave count: 147 wave-slots (l<32:1, 32..63:2, 64..80:3) x 32 b.

#define NTOT 6561
#define CH   64
#define NL   81
#define WTAB_ELEMS (NL * CH * CH)

// ---- Kernel A: interpolated weight table, wt[l][i][o] (o contiguous) ----
__global__ __launch_bounds__(256) void interp_kernel(const float* __restrict__ w,
                                                     float* __restrict__ wt) {
  int idx = blockIdx.x * 256 + threadIdx.x;   // 1296*256 = 331776 exact
  int l = idx >> 12;
  int i = (idx >> 6) & 63;
  int o = idx & 63;
  int cp; float f;
  if (l < 75) { cp = l / 5; f = (float)(l - cp * 5) * 0.2f; }
  else        { cp = 15;    f = (float)(l - 75) * 0.2f; }
  const float* wp = w + (size_t)(i * 64 + o) * 17 + cp;   // weight[i][o][cp]
  wt[idx] = (1.0f - f) * wp[0] + f * wp[1];
}

// ---- Main kernel: grid (147, 32), block = 64 (one wave) ----
__global__ __launch_bounds__(64) void shconv_main(const float* __restrict__ x,
                                                  const float* __restrict__ wt,
                                                  float* __restrict__ out) {
  const int slot = blockIdx.x;
  const int b = blockIdx.y;
  int l, wv;
  if (slot < 32)      { l = slot;                    wv = 0; }
  else if (slot < 96) { l = 32 + ((slot - 32) >> 1); wv = (slot - 32) & 1; }
  else                { l = 64 + (slot - 96) / 3;    wv = (slot - 96) % 3; }

  const int lane = threadIdx.x;
  const int P = 2 * l + 1;
  int poff = wv * 64 + lane;
  const bool active = poff < P;
  if (!active) poff = 0;                      // clamp: no OOB reads on tail wave
  const size_t n = (size_t)(l * l) + poff;

  const float* xb = x + (size_t)b * CH * NTOT + n;     // per-lane, coalesced
  const float* wl = wt + (size_t)l * 4096;             // block-uniform

  float acc[64];
#pragma unroll
  for (int o = 0; o < 64; ++o) acc[o] = 0.f;

#pragma unroll 4
  for (int i = 0; i < 64; ++i) {
    float xv = xb[(size_t)i * NTOT];                   // coalesced 256B/wave
    const float* wr = wl + i * 64;                     // uniform -> s_load
#pragma unroll
    for (int o = 0; o < 64; ++o)
      acc[o] = fmaf(xv, wr[o], acc[o]);                // v_fmac with SGPR src
  }

  if (active) {
    float* ob = out + (size_t)b * CH * NTOT + n;
#pragma unroll
    for (int o = 0; o < 64; ++o)
      ob[(size_t)o * NTOT] = acc[o];                   // coalesced 256B/wave
  }
}

// ---- Fallback (no workspace): R1's passing LDS kernel, unchanged ----
__global__ __launch_bounds__(192) void shconv_fallback(const float* __restrict__ x,
                                                       const float* __restrict__ w,
                                                       float* __restrict__ out) {
  __shared__ float wl[2][64][64];
  const int l1 = blockIdx.x;
  const int l2 = 80 - l1;
  const int P1 = 2 * l1 + 1;
  const int P2 = (l1 == 40) ? 0 : 2 * l2 + 1;
  int cp1, cp2; float f1, f2;
  if (l1 < 75) { cp1 = l1 / 5; f1 = (float)(l1 - cp1 * 5) * 0.2f; }
  else         { cp1 = 15;     f1 = (float)(l1 - 75) * 0.2f; }
  if (l2 < 75) { cp2 = l2 / 5; f2 = (float)(l2 - cp2 * 5) * 0.2f; }
  else         { cp2 = 15;     f2 = (float)(l2 - 75) * 0.2f; }
  const int tid = threadIdx.x;
  for (int e = tid; e < 8192; e += 192) {
    int sel = e >> 12, r = e & 4095, i = r >> 6, o = r & 63;
    int cp = sel ? cp2 : cp1;
    float f = sel ? f2 : f1;
    const float* wp = w + (size_t)(i * 64 + o) * 17 + cp;
    wl[sel][i][o] = (1.0f - f) * wp[0] + f * wp[1];
  }
  __syncthreads();
  const int Ptot = P1 + P2;
  if (tid >= Ptot) return;
  int sel, l, p;
  if (tid < P1) { sel = 0; l = l1; p = tid; }
  else          { sel = 1; l = l2; p = tid - P1; }
  const size_t nidx = (size_t)(l * l) + p;
  const int b0 = blockIdx.y, b1 = b0 + 16;
  const float* x0 = x + (size_t)b0 * CH * NTOT + nidx;
  const float* x1 = x + (size_t)b1 * CH * NTOT + nidx;
  float acc0[64], acc1[64];
#pragma unroll
  for (int o = 0; o < 64; ++o) { acc0[o] = 0.f; acc1[o] = 0.f; }
  const float* wbase = &wl[sel][0][0];
#pragma unroll 4
  for (int i = 0; i < 64; ++i) {
    float xv0 = x0[(size_t)i * NTOT];
    float xv1 = x1[(size_t)i * NTOT];
    const float* wr = wbase + i * 64;
#pragma unroll
    for (int o = 0; o < 64; o += 4) {
      float4 wv = *(const float4*)(wr + o);
      acc0[o]     = fmaf(xv0, wv.x, acc0[o]);
      acc0[o + 1] = fmaf(xv0, wv.y, acc0[o + 1]);
      acc0[o + 2] = fmaf(xv0, wv.z, acc0[o + 2]);
      acc0[o + 3] = fmaf(xv0, wv.w, acc0[o + 3]);
      acc1[o]     = fmaf(xv1, wv.x, acc1[o]);
      acc1[o + 1] = fmaf(xv1, wv.y, acc1[o + 1]);
      acc1[o + 2] = fmaf(xv1, wv.z, acc1[o + 2]);
      acc1[o + 3] = fmaf(xv1, wv.w, acc1[o + 3]);
    }
  }
  float* o0 = out + (size_t)b0 * CH * NTOT + nidx;
  float* o1 = out + (size_t)b1 * CH * NTOT + nidx;
#pragma unroll
  for (int o = 0; o < 64; ++o) {
    o0[(size_t)o * NTOT] = acc0[o];
    o1[(size_t)o * NTOT] = acc1[o];
  }
}

extern "C" void kernel_launch(void* const* d_in, const int* in_sizes, int n_in,
                              void* d_out, int out_size, void* d_ws, size_t ws_size,
                              hipStream_t stream) {
  const float* x = (const float*)d_in[0];
  const float* w = (const float*)d_in[1];
  float* out = (float*)d_out;

  if (ws_size >= (size_t)WTAB_ELEMS * sizeof(float) && d_ws != nullptr) {
    float* wt = (float*)d_ws;
    hipLaunchKernelGGL(interp_kernel, dim3(WTAB_ELEMS / 256), dim3(256), 0, stream, w, wt);
    hipLaunchKernelGGL(shconv_main, dim3(147, 32), dim3(64), 0, stream, x, wt, out);
  } else {
    hipLaunchKernelGGL(shconv_fallback, dim3(41, 16), dim3(192), 0, stream, x, w, out);
  }
}

// Round 4
// 37.505 us; speedup vs baseline: 9.7321x; 1.5197x over previous
//
#include <hip/hip_runtime.h>
#include <hip/hip_bf16.h>

// SHConv via bf16 MFMA: out[b,o,n] = sum_i x[b,i,n] * W_{l(n)}[i,o]
// x: (32,64,6561) f32, weight: (64,64,17,1) f32, out: (32,64,6561) f32
//
// Kernel A: interpolate control points -> bf16 table wtb[l][o][i] (81*64*64, 664 KB).
// Kernel B: one wave per (l, batch, 16-position chunk) computes the 64x16 output
// tile with 8x mfma_f32_16x16x32_bf16 (A = W^T 16ox32i, B = x 32ix16n, fp32 acc).
// All x loads and out stores are 64B-segment coalesced; weights come from L1/L2.

#define NTOT 6561
#define NL   81
#define CH   64
#define NSLOTS 451                       // sum over l of ceil((2l+1)/16)
#define WTB_BYTES (NL * CH * CH * 2)     // 663552

typedef __attribute__((ext_vector_type(8))) short bf16x8;
typedef __attribute__((ext_vector_type(4))) float f32x4;

// ---- Kernel A: bf16 interpolated weight table, wtb[l][o][i] (i contiguous) ----
__global__ __launch_bounds__(256) void interp_bf16(const float* __restrict__ w,
                                                   __hip_bfloat16* __restrict__ wtb) {
  int idx = blockIdx.x * 256 + threadIdx.x;   // 1296*256 = 331776 exact
  int l = idx >> 12;
  int o = (idx >> 6) & 63;
  int i = idx & 63;
  int cp; float f;
  if (l < 75) { cp = l / 5; f = (float)(l - cp * 5) * 0.2f; }
  else        { cp = 15;    f = (float)(l - 75) * 0.2f; }
  const float* wp = w + (size_t)(i * 64 + o) * 17 + cp;   // weight[i][o][cp]
  float v = (1.0f - f) * wp[0] + f * wp[1];
  wtb[(size_t)l * 4096 + o * 64 + i] = __float2bfloat16(v);
}

// ---- Kernel B: grid (113, 32), block 256 = 4 waves, wave slot s in [0,451) ----
__global__ __launch_bounds__(256) void shconv_mfma(const float* __restrict__ x,
                                                   const __hip_bfloat16* __restrict__ wtb,
                                                   float* __restrict__ out) {
  const int s = blockIdx.x * 4 + (threadIdx.x >> 6);
  if (s >= NSLOTS) return;
  const int b = blockIdx.y;

  // slot -> (l, chunk): group g = l/8 has g+1 chunks per l; 4g(g+1) chunks before it
  int g = 0;
  while (g < 10 && 4 * (g + 1) * (g + 2) <= s) ++g;
  const int r = s - 4 * g * (g + 1);
  const int l = 8 * g + r / (g + 1);
  const int c = r - (l - 8 * g) * (g + 1);
  const int P = 2 * l + 1;

  const int lane = threadIdx.x & 63;
  const int m  = lane & 15;          // position within chunk (B col / D col)
  const int kg = lane >> 4;          // k-group 0..3

  const int p = c * 16 + m;
  const int pl = (p < P) ? p : (P - 1);          // clamp tail loads in-bounds
  const size_t nbase = (size_t)l * l;
  const float* xb = x + (size_t)b * CH * NTOT + nbase + pl;

  // B fragments: lane holds x[i = ks*32 + kg*8 + j][pos m], j=0..7, as bf16
  float xraw[16];
#pragma unroll
  for (int ks = 0; ks < 2; ++ks)
#pragma unroll
    for (int j = 0; j < 8; ++j)
      xraw[ks * 8 + j] = xb[(size_t)(ks * 32 + kg * 8 + j) * NTOT];

  bf16x8 bfrag[2];
#pragma unroll
  for (int ks = 0; ks < 2; ++ks)
#pragma unroll
    for (int j = 0; j < 8; ++j) {
      __hip_bfloat16 h = __float2bfloat16(xraw[ks * 8 + j]);
      bfrag[ks][j] = *reinterpret_cast<short*>(&h);
    }

  // A fragments from wtb[l][o][i]: row o = t*16 + (lane&15), k i = ks*32 + kg*8 + j
  const __hip_bfloat16* wl = wtb + (size_t)l * 4096;
  f32x4 acc[4];
#pragma unroll
  for (int t = 0; t < 4; ++t) acc[t] = (f32x4)(0.0f);

#pragma unroll
  for (int ks = 0; ks < 2; ++ks) {
#pragma unroll
    for (int t = 0; t < 4; ++t) {
      const int o = t * 16 + m;
      const int i0 = ks * 32 + kg * 8;
      bf16x8 afrag = *reinterpret_cast<const bf16x8*>(wl + (size_t)o * 64 + i0);
      acc[t] = __builtin_amdgcn_mfma_f32_16x16x32_bf16(afrag, bfrag[ks], acc[t], 0, 0, 0);
    }
  }

  // D layout (verified): col = lane&15 (=m), row = kg*4 + reg within each 16-row tile
  if (p < P) {
    float* ob = out + (size_t)b * CH * NTOT + nbase + p;
#pragma unroll
    for (int t = 0; t < 4; ++t)
#pragma unroll
      for (int rg = 0; rg < 4; ++rg) {
        const int o = t * 16 + kg * 4 + rg;
        ob[(size_t)o * NTOT] = acc[t][rg];
      }
  }
}

// ---- Fallback (no workspace): R2's passing fp32 LDS kernel ----
__global__ __launch_bounds__(192) void shconv_fallback(const float* __restrict__ x,
                                                       const float* __restrict__ w,
                                                       float* __restrict__ out) {
  __shared__ float wl[2][64][64];
  const int l1 = blockIdx.x;
  const int l2 = 80 - l1;
  const int P1 = 2 * l1 + 1;
  const int P2 = (l1 == 40) ? 0 : 2 * l2 + 1;
  int cp1, cp2; float f1, f2;
  if (l1 < 75) { cp1 = l1 / 5; f1 = (float)(l1 - cp1 * 5) * 0.2f; }
  else         { cp1 = 15;     f1 = (float)(l1 - 75) * 0.2f; }
  if (l2 < 75) { cp2 = l2 / 5; f2 = (float)(l2 - cp2 * 5) * 0.2f; }
  else         { cp2 = 15;     f2 = (float)(l2 - 75) * 0.2f; }
  const int tid = threadIdx.x;
  for (int e = tid; e < 8192; e += 192) {
    int sel = e >> 12, rr = e & 4095, i = rr >> 6, o = rr & 63;
    int cp = sel ? cp2 : cp1;
    float f = sel ? f2 : f1;
    const float* wp = w + (size_t)(i * 64 + o) * 17 + cp;
    wl[sel][i][o] = (1.0f - f) * wp[0] + f * wp[1];
  }
  __syncthreads();
  const int Ptot = P1 + P2;
  if (tid >= Ptot) return;
  int sel, l, p;
  if (tid < P1) { sel = 0; l = l1; p = tid; }
  else          { sel = 1; l = l2; p = tid - P1; }
  const size_t nidx = (size_t)(l * l) + p;
  const int b0 = blockIdx.y, b1 = b0 + 16;
  const float* x0 = x + (size_t)b0 * CH * NTOT + nidx;
  const float* x1 = x + (size_t)b1 * CH * NTOT + nidx;
  float acc0[64], acc1[64];
#pragma unroll
  for (int o = 0; o < 64; ++o) { acc0[o] = 0.f; acc1[o] = 0.f; }
  const float* wbase = &wl[sel][0][0];
#pragma unroll 4
  for (int i = 0; i < 64; ++i) {
    float xv0 = x0[(size_t)i * NTOT];
    float xv1 = x1[(size_t)i * NTOT];
    const float* wr = wbase + i * 64;
#pragma unroll
    for (int o = 0; o < 64; o += 4) {
      float4 wv = *(const float4*)(wr + o);
      acc0[o]     = fmaf(xv0, wv.x, acc0[o]);
      acc0[o + 1] = fmaf(xv0, wv.y, acc0[o + 1]);
      acc0[o + 2] = fmaf(xv0, wv.z, acc0[o + 2]);
      acc0[o + 3] = fmaf(xv0, wv.w, acc0[o + 3]);
      acc1[o]     = fmaf(xv1, wv.x, acc1[o]);
      acc1[o + 1] = fmaf(xv1, wv.y, acc1[o + 1]);
      acc1[o + 2] = fmaf(xv1, wv.z, acc1[o + 2]);
      acc1[o + 3] = fmaf(xv1, wv.w, acc1[o + 3]);
    }
  }
  float* o0 = out + (size_t)b0 * CH * NTOT + nidx;
  float* o1 = out + (size_t)b1 * CH * NTOT + nidx;
#pragma unroll
  for (int o = 0; o < 64; ++o) {
    o0[(size_t)o * NTOT] = acc0[o];
    o1[(size_t)o * NTOT] = acc1[o];
  }
}

extern "C" void kernel_launch(void* const* d_in, const int* in_sizes, int n_in,
                              void* d_out, int out_size, void* d_ws, size_t ws_size,
                              hipStream_t stream) {
  const float* x = (const float*)d_in[0];
  const float* w = (const float*)d_in[1];
  float* out = (float*)d_out;

  if (ws_size >= (size_t)WTB_BYTES && d_ws != nullptr) {
    __hip_bfloat16* wtb = (__hip_bfloat16*)d_ws;
    hipLaunchKernelGGL(interp_bf16, dim3(1296), dim3(256), 0, stream, w, wtb);
    hipLaunchKernelGGL(shconv_mfma, dim3(113, 32), dim3(256), 0, stream, x, wtb, out);
  } else {
    hipLaunchKernelGGL(shconv_fallback, dim3(41, 16), dim3(192), 0, stream, x, w, out);
  }
}

// Round 5
// 36.860 us; speedup vs baseline: 9.9023x; 1.0175x over previous
//
#include <hip/hip_runtime.h>
#include <hip/hip_bf16.h>

// SHConv via bf16 MFMA: out[b,o,n] = sum_i x[b,i,n] * W_{l(n)}[i,o]
// x: (32,64,6561) f32, weight: (64,64,17,1) f32, out: (32,64,6561) f32
//
// Kernel A: interpolate control points -> bf16 table wtb[l][o][i] (81*64*64, 664 KB).
// Kernel B: one wave per (l, 16-position chunk, batch-PAIR): computes the 64x16
// output tile for batches b and b+16 with 16x mfma_f32_16x16x32_bf16, sharing the
// A (weight) fragments. 32 independent x-loads in flight per wave (2x R3's ILP),
// half the waves, half the weight traffic. Loads/stores stay 64B-coalesced.

#define NTOT 6561
#define NL   81
#define CH   64
#define NSLOTS 451                       // sum over l of ceil((2l+1)/16)
#define WTB_BYTES (NL * CH * CH * 2)     // 663552

typedef __attribute__((ext_vector_type(8))) short bf16x8;
typedef __attribute__((ext_vector_type(4))) float f32x4;

// ---- Kernel A: bf16 interpolated weight table, wtb[l][o][i] (i contiguous) ----
__global__ __launch_bounds__(256) void interp_bf16(const float* __restrict__ w,
                                                   __hip_bfloat16* __restrict__ wtb) {
  int idx = blockIdx.x * 256 + threadIdx.x;   // 1296*256 = 331776 exact
  int l = idx >> 12;
  int o = (idx >> 6) & 63;
  int i = idx & 63;
  int cp; float f;
  if (l < 75) { cp = l / 5; f = (float)(l - cp * 5) * 0.2f; }
  else        { cp = 15;    f = (float)(l - 75) * 0.2f; }
  const float* wp = w + (size_t)(i * 64 + o) * 17 + cp;   // weight[i][o][cp]
  float v = (1.0f - f) * wp[0] + f * wp[1];
  wtb[(size_t)l * 4096 + o * 64 + i] = __float2bfloat16(v);
}

// ---- Kernel B: grid (113, 16), block 256 = 4 waves; wave = (slot, batch-pair) ----
__global__ __launch_bounds__(256) void shconv_mfma2(const float* __restrict__ x,
                                                    const __hip_bfloat16* __restrict__ wtb,
                                                    float* __restrict__ out) {
  const int s = blockIdx.x * 4 + (threadIdx.x >> 6);
  if (s >= NSLOTS) return;
  const int b0 = blockIdx.y;         // 0..15
  const int b1 = b0 + 16;

  // slot -> (l, chunk): group g = l/8 has g+1 chunks per l; 4g(g+1) chunks before it
  int g = 0;
  while (g < 10 && 4 * (g + 1) * (g + 2) <= s) ++g;
  const int r = s - 4 * g * (g + 1);
  const int l = 8 * g + r / (g + 1);
  const int c = r - (l - 8 * g) * (g + 1);
  const int P = 2 * l + 1;

  const int lane = threadIdx.x & 63;
  const int m  = lane & 15;          // position within chunk (B col / D col)
  const int kg = lane >> 4;          // k-group 0..3

  const int p = c * 16 + m;
  const int pl = (p < P) ? p : (P - 1);          // clamp tail loads in-bounds
  const size_t nbase = (size_t)l * l;
  const float* xb0 = x + (size_t)b0 * CH * NTOT + nbase + pl;
  const float* xb1 = x + (size_t)b1 * CH * NTOT + nbase + pl;

  // 32 independent coalesced loads (issued before any dependent convert/MFMA)
  float xr0[16], xr1[16];
#pragma unroll
  for (int ks = 0; ks < 2; ++ks)
#pragma unroll
    for (int j = 0; j < 8; ++j) {
      const size_t off = (size_t)(ks * 32 + kg * 8 + j) * NTOT;
      xr0[ks * 8 + j] = xb0[off];
      xr1[ks * 8 + j] = xb1[off];
    }

  bf16x8 bf0[2], bf1[2];
#pragma unroll
  for (int ks = 0; ks < 2; ++ks)
#pragma unroll
    for (int j = 0; j < 8; ++j) {
      __hip_bfloat16 h0 = __float2bfloat16(xr0[ks * 8 + j]);
      __hip_bfloat16 h1 = __float2bfloat16(xr1[ks * 8 + j]);
      bf0[ks][j] = *reinterpret_cast<short*>(&h0);
      bf1[ks][j] = *reinterpret_cast<short*>(&h1);
    }

  // A fragments from wtb[l][o][i]: row o = t*16 + m, k i = ks*32 + kg*8 + j (shared)
  const __hip_bfloat16* wl = wtb + (size_t)l * 4096;
  f32x4 acc0[4], acc1[4];
#pragma unroll
  for (int t = 0; t < 4; ++t) { acc0[t] = (f32x4)(0.0f); acc1[t] = (f32x4)(0.0f); }

#pragma unroll
  for (int ks = 0; ks < 2; ++ks) {
#pragma unroll
    for (int t = 0; t < 4; ++t) {
      const int o = t * 16 + m;
      const int i0 = ks * 32 + kg * 8;
      bf16x8 afrag = *reinterpret_cast<const bf16x8*>(wl + (size_t)o * 64 + i0);
      acc0[t] = __builtin_amdgcn_mfma_f32_16x16x32_bf16(afrag, bf0[ks], acc0[t], 0, 0, 0);
      acc1[t] = __builtin_amdgcn_mfma_f32_16x16x32_bf16(afrag, bf1[ks], acc1[t], 0, 0, 0);
    }
  }

  // D layout (verified m89): col = lane&15 (=m), row = kg*4 + reg per 16-row tile
  if (p < P) {
    float* ob0 = out + (size_t)b0 * CH * NTOT + nbase + p;
    float* ob1 = out + (size_t)b1 * CH * NTOT + nbase + p;
#pragma unroll
    for (int t = 0; t < 4; ++t)
#pragma unroll
      for (int rg = 0; rg < 4; ++rg) {
        const int o = t * 16 + kg * 4 + rg;
        ob0[(size_t)o * NTOT] = acc0[t][rg];
        ob1[(size_t)o * NTOT] = acc1[t][rg];
      }
  }
}

// ---- Fallback (no workspace): R2's passing fp32 LDS kernel ----
__global__ __launch_bounds__(192) void shconv_fallback(const float* __restrict__ x,
                                                       const float* __restrict__ w,
                                                       float* __restrict__ out) {
  __shared__ float wl[2][64][64];
  const int l1 = blockIdx.x;
  const int l2 = 80 - l1;
  const int P1 = 2 * l1 + 1;
  const int P2 = (l1 == 40) ? 0 : 2 * l2 + 1;
  int cp1, cp2; float f1, f2;
  if (l1 < 75) { cp1 = l1 / 5; f1 = (float)(l1 - cp1 * 5) * 0.2f; }
  else         { cp1 = 15;     f1 = (float)(l1 - 75) * 0.2f; }
  if (l2 < 75) { cp2 = l2 / 5; f2 = (float)(l2 - cp2 * 5) * 0.2f; }
  else         { cp2 = 15;     f2 = (float)(l2 - 75) * 0.2f; }
  const int tid = threadIdx.x;
  for (int e = tid; e < 8192; e += 192) {
    int sel = e >> 12, rr = e & 4095, i = rr >> 6, o = rr & 63;
    int cp = sel ? cp2 : cp1;
    float f = sel ? f2 : f1;
    const float* wp = w + (size_t)(i * 64 + o) * 17 + cp;
    wl[sel][i][o] = (1.0f - f) * wp[0] + f * wp[1];
  }
  __syncthreads();
  const int Ptot = P1 + P2;
  if (tid >= Ptot) return;
  int sel, l, p;
  if (tid < P1) { sel = 0; l = l1; p = tid; }
  else          { sel = 1; l = l2; p = tid - P1; }
  const size_t nidx = (size_t)(l * l) + p;
  const int b0 = blockIdx.y, b1 = b0 + 16;
  const float* x0 = x + (size_t)b0 * CH * NTOT + nidx;
  const float* x1 = x + (size_t)b1 * CH * NTOT + nidx;
  float acc0[64], acc1[64];
#pragma unroll
  for (int o = 0; o < 64; ++o) { acc0[o] = 0.f; acc1[o] = 0.f; }
  const float* wbase = &wl[sel][0][0];
#pragma unroll 4
  for (int i = 0; i < 64; ++i) {
    float xv0 = x0[(size_t)i * NTOT];
    float xv1 = x1[(size_t)i * NTOT];
    const float* wr = wbase + i * 64;
#pragma unroll
    for (int o = 0; o < 64; o += 4) {
      float4 wv = *(const float4*)(wr + o);
      acc0[o]     = fmaf(xv0, wv.x, acc0[o]);
      acc0[o + 1] = fmaf(xv0, wv.y, acc0[o + 1]);
      acc0[o + 2] = fmaf(xv0, wv.z, acc0[o + 2]);
      acc0[o + 3] = fmaf(xv0, wv.w, acc0[o + 3]);
      acc1[o]     = fmaf(xv1, wv.x, acc1[o]);
      acc1[o + 1] = fmaf(xv1, wv.y, acc1[o + 1]);
      acc1[o + 2] = fmaf(xv1, wv.z, acc1[o + 2]);
      acc1[o + 3] = fmaf(xv1, wv.w, acc1[o + 3]);
    }
  }
  float* o0 = out + (size_t)b0 * CH * NTOT + nidx;
  float* o1 = out + (size_t)b1 * CH * NTOT + nidx;
#pragma unroll
  for (int o = 0; o < 64; ++o) {
    o0[(size_t)o * NTOT] = acc0[o];
    o1[(size_t)o * NTOT] = acc1[o];
  }
}

extern "C" void kernel_launch(void* const* d_in, const int* in_sizes, int n_in,
                              void* d_out, int out_size, void* d_ws, size_t ws_size,
                              hipStream_t stream) {
  const float* x = (const float*)d_in[0];
  const float* w = (const float*)d_in[1];
  float* out = (float*)d_out;

  if (ws_size >= (size_t)WTB_BYTES && d_ws != nullptr) {
    __hip_bfloat16* wtb = (__hip_bfloat16*)d_ws;
    hipLaunchKernelGGL(interp_bf16, dim3(1296), dim3(256), 0, stream, w, wtb);
    hipLaunchKernelGGL(shconv_mfma2, dim3(113, 16), dim3(256), 0, stream, x, wtb, out);
  } else {
    hipLaunchKernelGGL(shconv_fallback, dim3(41, 16), dim3(192), 0, stream, x, w, out);
  }
}